// Round 5
// baseline (138.557 us; speedup 1.0000x reference)
//
#include <hip/hip_runtime.h>
#include <hip/hip_bf16.h>

#define NN 50000
#define CC 64
#define KK 20
#define NTILES 3125          // 16-node tiles
#define EDGE_BLOCKS 1563     // 2 tiles per block; 6.1 blocks/CU -> no dispatch tail

static __device__ __forceinline__ ushort f2bf(float f) {
    unsigned int u = __float_as_uint(f);
    unsigned int r = (u + 0x7FFFu + ((u >> 16) & 1u)) >> 16;   // RNE
    return (ushort)r;
}
static __device__ __forceinline__ float bfl(unsigned int u) {   // low bf16 -> f32
    return __uint_as_float(u << 16);
}
static __device__ __forceinline__ float bfh(unsigned int u) {   // high bf16 -> f32
    return __uint_as_float(u & 0xffff0000u);
}

// ---------------------------------------------------------------------------
// Kernel 1 (unchanged): yA[n][c] = (W1-W2)@x + b ; yB[n][c] = W2@x,
// node-major bf16 (one node column = 128 B = one cache line).
// ---------------------------------------------------------------------------
__global__ __launch_bounds__(256) void prep_kernel(
    const float* __restrict__ x,   // [64][NN]
    const float* __restrict__ W,   // [64][128]
    const float* __restrict__ b,   // [64]
    ushort* __restrict__ yA,       // [NN][64] bf16
    ushort* __restrict__ yB)       // [NN][64] bf16
{
    __shared__ float At[64][65];
    __shared__ float Bt[64][65];
    __shared__ float xt[64][68];

    const int t = threadIdx.x;
    for (int i = t; i < 64 * 64; i += 256) {
        int c = i >> 6, ci = i & 63;
        float w1 = W[c * 128 + ci];
        float w2 = W[c * 128 + 64 + ci];
        At[ci][c] = w1 - w2;
        Bt[ci][c] = w2;
    }

    const int n0 = blockIdx.x * 64;
    const int g  = t >> 6;
    const int nl = t & 63;
    #pragma unroll
    for (int i = 0; i < 16; i++) {
        int ci = i * 4 + g;
        int nn = n0 + nl;
        xt[ci][nl] = (nn < NN) ? x[ci * NN + nn] : 0.f;
    }
    __syncthreads();

    const int c = t & 63;
    float accA[16], accB[16];
    #pragma unroll
    for (int j = 0; j < 16; j++) { accA[j] = 0.f; accB[j] = 0.f; }

    for (int ci = 0; ci < 64; ci++) {
        float a  = At[ci][c];
        float w2 = Bt[ci][c];
        const float4* xr = reinterpret_cast<const float4*>(&xt[ci][g * 16]);
        #pragma unroll
        for (int q = 0; q < 4; q++) {
            float4 xv = xr[q];
            accA[q * 4 + 0] += a * xv.x;  accB[q * 4 + 0] += w2 * xv.x;
            accA[q * 4 + 1] += a * xv.y;  accB[q * 4 + 1] += w2 * xv.y;
            accA[q * 4 + 2] += a * xv.z;  accB[q * 4 + 2] += w2 * xv.z;
            accA[q * 4 + 3] += a * xv.w;  accB[q * 4 + 3] += w2 * xv.w;
        }
    }

    float bias = b[c];
    #pragma unroll
    for (int j = 0; j < 16; j++) {
        int n = n0 + g * 16 + j;
        if (n < NN) {
            yA[n * 64 + c] = f2bf(accA[j] + bias);
            yB[n * 64 + c] = f2bf(accB[j]);
        }
    }
}

// ---------------------------------------------------------------------------
// Kernel 2: grid 1563 x 256; each block handles TWO 16-node tiles so all
// blocks are co-resident (6.1/CU <= 8) -> no ragged dispatch tail (R2 showed
// 52% occupancy from the 12.2-blocks/CU tail). Per tile: 4 nodes/wave,
// slot-parallel gather (4 edge slots x 16 channel-quads), idx/sup staged in
// LDS, all 10 gathers in flight per node. ReLU folded into the max (m>=0,
// sup>=0 -> max(m, v*sup) is exact). Channel math on float2 for v_pk_* ops.
// ---------------------------------------------------------------------------
__global__ __launch_bounds__(256) void edge_kernel(
    const ushort* __restrict__ yA,   // [NN][64] bf16  (x_i path, edge_index[1])
    const ushort* __restrict__ yB,   // [NN][64] bf16  (x_j path, edge_index[0])
    const int* __restrict__ ej,      // edge_index[0] : [NN][KK]
    const int* __restrict__ ei,      // edge_index[1] : [NN][KK]
    const float* __restrict__ dis,   // [NN][KK]
    const float* __restrict__ att_w, // [KK]
    const float* __restrict__ att_b, // [1]
    float* __restrict__ out)         // [64][NN]
{
    __shared__ float supL[16][KK];       // 2*sigmoid(-d*scaler) per (node,k)
    __shared__ unsigned int ijL[16][KK]; // i | (j<<16)   (both < 50000 < 2^16)
    __shared__ float tile[16][68];

    const int t    = threadIdx.x;
    const int lane = t & 63;
    const int w    = t >> 6;            // wave 0..3
    const int g    = lane >> 4;         // edge slot 0..3
    const int l    = lane & 15;         // channel quad (uint2 within column)

    const float aw = (lane < KK) ? att_w[lane] : 0.f;
    const float ab = att_b[0];

    const uint2* A2 = (const uint2*)yA;   // 16 uint2 per node column
    const uint2* B2 = (const uint2*)yB;

    #pragma unroll
    for (int ti = 0; ti < 2; ti++) {
        const int tidx  = blockIdx.x * 2 + ti;
        const bool ok   = (tidx < NTILES);
        const int n0    = tidx * 16;

        if (ok) {
            // ---- Stage: each wave stages its own 4 nodes (producer ==
            // consumer wave; ordered by lgkmcnt, no barrier needed). ----
            #pragma unroll
            for (int s = 0; s < 4; s++) {
                const int nl = w * 4 + s;
                const int n  = n0 + nl;
                float d = 0.f; int ii = 0, jj = 0;
                if (lane < KK) {
                    d  = dis[n * KK + lane];
                    ii = ei[n * KK + lane];
                    jj = ej[n * KK + lane];
                }
                float p = aw * d;
                #pragma unroll
                for (int off = 16; off > 0; off >>= 1) p += __shfl_down(p, off);
                const float scaler = tanhf(__shfl(p, 0) + ab) + 1.0f;
                if (lane < KK) {
                    supL[nl][lane] = 2.0f / (1.0f + __expf(d * scaler));
                    ijL[nl][lane]  = (unsigned int)ii | ((unsigned int)jj << 16);
                }
            }

            #pragma unroll
            for (int s = 0; s < 4; s++) {
                const int nl = w * 4 + s;

                unsigned int ij[5]; float sp[5];
                #pragma unroll
                for (int kb = 0; kb < 5; kb++) {        // 16-lane broadcast reads
                    ij[kb] = ijL[nl][kb * 4 + g];
                    sp[kb] = supL[nl][kb * 4 + g];
                }

                uint2 av[5], bv[5];
                #pragma unroll
                for (int kb = 0; kb < 5; kb++) {        // 10 gathers in flight
                    const unsigned int i_k = ij[kb] & 0xffffu;
                    const unsigned int j_k = ij[kb] >> 16;
                    av[kb] = A2[(size_t)i_k * 16 + l];
                    bv[kb] = B2[(size_t)j_k * 16 + l];
                }

                float2 m0 = {0.f, 0.f}, m1 = {0.f, 0.f};
                #pragma unroll
                for (int kb = 0; kb < 5; kb++) {
                    const float s_k = sp[kb];
                    float2 v0, v1;                       // (a+b)*s, packed pairs
                    v0.x = (bfl(av[kb].x) + bfl(bv[kb].x)) * s_k;
                    v0.y = (bfh(av[kb].x) + bfh(bv[kb].x)) * s_k;
                    v1.x = (bfl(av[kb].y) + bfl(bv[kb].y)) * s_k;
                    v1.y = (bfh(av[kb].y) + bfh(bv[kb].y)) * s_k;
                    m0.x = fmaxf(m0.x, v0.x);  m0.y = fmaxf(m0.y, v0.y);
                    m1.x = fmaxf(m1.x, v1.x);  m1.y = fmaxf(m1.y, v1.y);
                }

                // max across the 4 slots
                #pragma unroll
                for (int mask = 16; mask <= 32; mask <<= 1) {
                    m0.x = fmaxf(m0.x, __shfl_xor(m0.x, mask));
                    m0.y = fmaxf(m0.y, __shfl_xor(m0.y, mask));
                    m1.x = fmaxf(m1.x, __shfl_xor(m1.x, mask));
                    m1.y = fmaxf(m1.y, __shfl_xor(m1.y, mask));
                }
                if (g == 0) {
                    float4 mm = {m0.x, m0.y, m1.x, m1.y};
                    *(float4*)&tile[nl][l * 4] = mm;
                }
            }
        }
        __syncthreads();

        if (ok) {
            #pragma unroll
            for (int it = 0; it < 4; it++) {
                const int c  = it * 16 + (t >> 4);
                const int nl = t & 15;
                out[(size_t)c * NN + n0 + nl] = tile[nl][c];
            }
        }
        __syncthreads();   // tile[] reuse fence for the next iteration
    }
}

extern "C" void kernel_launch(void* const* d_in, const int* in_sizes, int n_in,
                              void* d_out, int out_size, void* d_ws, size_t ws_size,
                              hipStream_t stream) {
    const float* x     = (const float*)d_in[0];
    const int*   e     = (const int*)d_in[1];    // [2][NN][KK]
    const float* dis   = (const float*)d_in[2];
    const float* W     = (const float*)d_in[3];
    const float* b     = (const float*)d_in[4];
    const float* att_w = (const float*)d_in[5];
    const float* att_b = (const float*)d_in[6];
    float* out = (float*)d_out;

    ushort* yA = (ushort*)d_ws;                  // [NN][64] bf16
    ushort* yB = yA + (size_t)NN * 64;           // [NN][64] bf16 (12.8 MB total)

    prep_kernel<<<(NN + 63) / 64, 256, 0, stream>>>(x, W, b, yA, yB);
    edge_kernel<<<EDGE_BLOCKS, 256, 0, stream>>>(yA, yB, e, e + NN * KK, dis,
                                                 att_w, att_b, out);
}

// Round 6
// 137.300 us; speedup vs baseline: 1.0092x; 1.0092x over previous
//
#include <hip/hip_runtime.h>
#include <hip/hip_bf16.h>

#define NN 50000
#define CC 64
#define KK 20

static __device__ __forceinline__ ushort f2bf(float f) {
    unsigned int u = __float_as_uint(f);
    unsigned int r = (u + 0x7FFFu + ((u >> 16) & 1u)) >> 16;   // RNE
    return (ushort)r;
}
static __device__ __forceinline__ float bfl(unsigned int u) {   // low bf16 -> f32
    return __uint_as_float(u << 16);
}
static __device__ __forceinline__ float bfh(unsigned int u) {   // high bf16 -> f32
    return __uint_as_float(u & 0xffff0000u);
}

// ---------------------------------------------------------------------------
// Kernel 1 (unchanged): yA[n][c] = (W1-W2)@x + b ; yB[n][c] = W2@x,
// node-major bf16 (one node column = 128 B = one cache line).
// ---------------------------------------------------------------------------
__global__ __launch_bounds__(256) void prep_kernel(
    const float* __restrict__ x,   // [64][NN]
    const float* __restrict__ W,   // [64][128]
    const float* __restrict__ b,   // [64]
    ushort* __restrict__ yA,       // [NN][64] bf16
    ushort* __restrict__ yB)       // [NN][64] bf16
{
    __shared__ float At[64][65];
    __shared__ float Bt[64][65];
    __shared__ float xt[64][68];

    const int t = threadIdx.x;
    for (int i = t; i < 64 * 64; i += 256) {
        int c = i >> 6, ci = i & 63;
        float w1 = W[c * 128 + ci];
        float w2 = W[c * 128 + 64 + ci];
        At[ci][c] = w1 - w2;
        Bt[ci][c] = w2;
    }

    const int n0 = blockIdx.x * 64;
    const int g  = t >> 6;
    const int nl = t & 63;
    #pragma unroll
    for (int i = 0; i < 16; i++) {
        int ci = i * 4 + g;
        int nn = n0 + nl;
        xt[ci][nl] = (nn < NN) ? x[ci * NN + nn] : 0.f;
    }
    __syncthreads();

    const int c = t & 63;
    float accA[16], accB[16];
    #pragma unroll
    for (int j = 0; j < 16; j++) { accA[j] = 0.f; accB[j] = 0.f; }

    for (int ci = 0; ci < 64; ci++) {
        float a  = At[ci][c];
        float w2 = Bt[ci][c];
        const float4* xr = reinterpret_cast<const float4*>(&xt[ci][g * 16]);
        #pragma unroll
        for (int q = 0; q < 4; q++) {
            float4 xv = xr[q];
            accA[q * 4 + 0] += a * xv.x;  accB[q * 4 + 0] += w2 * xv.x;
            accA[q * 4 + 1] += a * xv.y;  accB[q * 4 + 1] += w2 * xv.y;
            accA[q * 4 + 2] += a * xv.z;  accB[q * 4 + 2] += w2 * xv.z;
            accA[q * 4 + 3] += a * xv.w;  accB[q * 4 + 3] += w2 * xv.w;
        }
    }

    float bias = b[c];
    #pragma unroll
    for (int j = 0; j < 16; j++) {
        int n = n0 + g * 16 + j;
        if (n < NN) {
            yA[n * 64 + c] = f2bf(accA[j] + bias);
            yB[n * 64 + c] = f2bf(accB[j]);
        }
    }
}

// ---------------------------------------------------------------------------
// Kernel 2: 16 nodes/block, 4 nodes/wave. 8 edge slots x 8 channel-octs:
// each lane loads uint4 (16B = 8 bf16 channels); 8 lanes cover one 128B
// column -> one wave-load gathers 8 edges. k covered by 3 blocks of 8 with
// min(k,19) clamp (dups exact under max). Cross-node software pipeline:
// node s+1's 6 gathers issued before consuming node s -> memory pipe never
// drains (~96 lines in flight/wave, 2.4x R3).
// ---------------------------------------------------------------------------
__global__ __launch_bounds__(256) void edge_kernel(
    const ushort* __restrict__ yA,   // [NN][64] bf16  (x_i path, edge_index[1])
    const ushort* __restrict__ yB,   // [NN][64] bf16  (x_j path, edge_index[0])
    const int* __restrict__ ej,      // edge_index[0] : [NN][KK]
    const int* __restrict__ ei,      // edge_index[1] : [NN][KK]
    const float* __restrict__ dis,   // [NN][KK]
    const float* __restrict__ att_w, // [KK]
    const float* __restrict__ att_b, // [1]
    float* __restrict__ out)         // [64][NN]
{
    __shared__ float tile[16][68];   // row stride 272B (17x16B): float4-aligned

    const int t    = threadIdx.x;
    const int lane = t & 63;
    const int w    = t >> 6;            // wave 0..3
    const int g    = lane >> 3;         // edge slot 0..7
    const int l    = lane & 7;          // channel oct: channels 8l..8l+7
    const int n0   = blockIdx.x * 16;   // grid 3125, no tail

    const float aw = (lane < KK) ? att_w[lane] : 0.f;
    const float ab = att_b[0];

    // ---- per-node edge data in lanes < 20 ----
    float d4[4]; int ii4[4], jj4[4];
    #pragma unroll
    for (int s = 0; s < 4; s++) {
        const int n = n0 + w * 4 + s;
        float d = 0.f; int ii = 0, jj = 0;
        if (lane < KK) {
            d  = dis[n * KK + lane];
            ii = ei[n * KK + lane];
            jj = ej[n * KK + lane];
        }
        d4[s] = d; ii4[s] = ii; jj4[s] = jj;
    }
    float sup4[4];
    #pragma unroll
    for (int s = 0; s < 4; s++) {
        float p = aw * d4[s];
        #pragma unroll
        for (int off = 16; off > 0; off >>= 1) p += __shfl_down(p, off);
        const float scaler = tanhf(__shfl(p, 0) + ab) + 1.0f;
        sup4[s] = 2.0f / (1.0f + __expf(d4[s] * scaler));  // valid lanes < 20
    }

    const uint4* A4 = (const uint4*)yA;   // 8 uint4 per node column
    const uint4* B4 = (const uint4*)yB;

    // slot g, block kb handles edge min(kb*8+g, 19); dups of 19 are exact
    const int src0 = (0 * 8 + g);                       // 0..7
    const int src1 = (1 * 8 + g);                       // 8..15
    const int src2 = (2 * 8 + g) > 19 ? 19 : (16 + g);  // 16..19 (clamped)

    uint4 av[2][3], bv[2][3];

    #define ISSUE(s, buf)                                                     \
        {                                                                     \
            const int i0 = __shfl(ii4[s], src0), j0 = __shfl(jj4[s], src0);   \
            const int i1 = __shfl(ii4[s], src1), j1 = __shfl(jj4[s], src1);   \
            const int i2 = __shfl(ii4[s], src2), j2 = __shfl(jj4[s], src2);   \
            av[buf][0] = A4[(size_t)i0 * 8 + l];                              \
            bv[buf][0] = B4[(size_t)j0 * 8 + l];                              \
            av[buf][1] = A4[(size_t)i1 * 8 + l];                              \
            bv[buf][1] = B4[(size_t)j1 * 8 + l];                              \
            av[buf][2] = A4[(size_t)i2 * 8 + l];                              \
            bv[buf][2] = B4[(size_t)j2 * 8 + l];                              \
        }

    ISSUE(0, 0)

    #pragma unroll
    for (int s = 0; s < 4; s++) {
        if (s < 3) {
            if (s == 0) ISSUE(1, 1)
            if (s == 1) ISSUE(2, 0)
            if (s == 2) ISSUE(3, 1)
        }
        const int buf = s & 1;
        const float sp0 = __shfl(sup4[s], src0);
        const float sp1 = __shfl(sup4[s], src1);
        const float sp2 = __shfl(sup4[s], src2);

        float m[8];
        #pragma unroll
        for (int c = 0; c < 8; c++) m[c] = 0.f;

        #pragma unroll
        for (int kb = 0; kb < 3; kb++) {
            const float s_k = (kb == 0) ? sp0 : (kb == 1) ? sp1 : sp2;
            const uint4 a = av[buf][kb];
            const uint4 bb = bv[buf][kb];
            m[0] = fmaxf(m[0], (bfl(a.x) + bfl(bb.x)) * s_k);
            m[1] = fmaxf(m[1], (bfh(a.x) + bfh(bb.x)) * s_k);
            m[2] = fmaxf(m[2], (bfl(a.y) + bfl(bb.y)) * s_k);
            m[3] = fmaxf(m[3], (bfh(a.y) + bfh(bb.y)) * s_k);
            m[4] = fmaxf(m[4], (bfl(a.z) + bfl(bb.z)) * s_k);
            m[5] = fmaxf(m[5], (bfh(a.z) + bfh(bb.z)) * s_k);
            m[6] = fmaxf(m[6], (bfl(a.w) + bfl(bb.w)) * s_k);
            m[7] = fmaxf(m[7], (bfh(a.w) + bfh(bb.w)) * s_k);
        }

        // max across the 8 slots (lanes with equal l)
        #pragma unroll
        for (int mask = 8; mask <= 32; mask <<= 1) {
            #pragma unroll
            for (int c = 0; c < 8; c++) m[c] = fmaxf(m[c], __shfl_xor(m[c], mask));
        }

        if (g == 0) {
            const int nl = w * 4 + s;
            float4 lo = {m[0], m[1], m[2], m[3]};
            float4 hi = {m[4], m[5], m[6], m[7]};
            *(float4*)&tile[nl][l * 8]     = lo;
            *(float4*)&tile[nl][l * 8 + 4] = hi;
        }
    }
    #undef ISSUE
    __syncthreads();

    // out[c][n0..n0+15]; coalesced 64B segments.
    #pragma unroll
    for (int it = 0; it < 4; it++) {
        const int c  = it * 16 + (t >> 4);
        const int nl = t & 15;
        out[(size_t)c * NN + n0 + nl] = tile[nl][c];
    }
}

extern "C" void kernel_launch(void* const* d_in, const int* in_sizes, int n_in,
                              void* d_out, int out_size, void* d_ws, size_t ws_size,
                              hipStream_t stream) {
    const float* x     = (const float*)d_in[0];
    const int*   e     = (const int*)d_in[1];    // [2][NN][KK]
    const float* dis   = (const float*)d_in[2];
    const float* W     = (const float*)d_in[3];
    const float* b     = (const float*)d_in[4];
    const float* att_w = (const float*)d_in[5];
    const float* att_b = (const float*)d_in[6];
    float* out = (float*)d_out;

    ushort* yA = (ushort*)d_ws;                  // [NN][64] bf16
    ushort* yB = yA + (size_t)NN * 64;           // [NN][64] bf16 (12.8 MB total)

    prep_kernel<<<(NN + 63) / 64, 256, 0, stream>>>(x, W, b, yA, yB);
    edge_kernel<<<NN / 16, 256, 0, stream>>>(yA, yB, e, e + NN * KK, dis,
                                             att_w, att_b, out);
}

// Round 7
// 127.446 us; speedup vs baseline: 1.0872x; 1.0773x over previous
//
#include <hip/hip_runtime.h>
#include <hip/hip_bf16.h>

#define NN 50000
#define CC 64
#define KK 20

static __device__ __forceinline__ ushort f2bf(float f) {
    unsigned int u = __float_as_uint(f);
    unsigned int r = (u + 0x7FFFu + ((u >> 16) & 1u)) >> 16;   // RNE
    return (ushort)r;
}
static __device__ __forceinline__ float bfl(unsigned int u) {   // low bf16 -> f32
    return __uint_as_float(u << 16);
}
static __device__ __forceinline__ float bfh(unsigned int u) {   // high bf16 -> f32
    return __uint_as_float(u & 0xffff0000u);
}

// ---------------------------------------------------------------------------
// Kernel 1: yA[n][c] = (W1-W2)@x + b ; yB[n][c] = W2@x, node-major bf16.
// R7 rewrite: prep was LDS-BW-bound (~2.25 B LDS read per FMA). Register
// tile = 2 ADJACENT channels x 16 nodes per thread (128-node blocks):
// At/Bt read as float2, xt reads amortized over 2 channels -> 1.25 B/FMA;
// stores pack both channels into one uint.
// ---------------------------------------------------------------------------
__global__ __launch_bounds__(256) void prep_kernel(
    const float* __restrict__ x,   // [64][NN]
    const float* __restrict__ W,   // [64][128]
    const float* __restrict__ b,   // [64]
    ushort* __restrict__ yA,       // [NN][64] bf16
    ushort* __restrict__ yB)       // [NN][64] bf16
{
    __shared__ float At[64][66];   // row = 264 B (8B-aligned for float2)
    __shared__ float Bt[64][66];
    __shared__ float xt[64][132];  // row = 528 B (16B-aligned for float4)

    const int t = threadIdx.x;
    for (int i = t; i < 64 * 64; i += 256) {
        int c = i >> 6, ci = i & 63;
        float w1 = W[c * 128 + ci];
        float w2 = W[c * 128 + 64 + ci];
        At[ci][c] = w1 - w2;
        Bt[ci][c] = w2;
    }

    const int n0 = blockIdx.x * 128;     // grid 391; tail block has 80 valid
    {
        const int q  = t & 31;           // float4 index within the 128 nodes
        const int cb = t >> 5;           // 0..7
        const float4* x4 = (const float4*)x;   // [64][12500] float4
        const int nq = (n0 >> 2) + q;
        #pragma unroll
        for (int i = 0; i < 8; i++) {
            const int ci = cb * 8 + i;
            float4 v = (nq < 12500) ? x4[ci * 12500 + nq]
                                    : float4{0.f, 0.f, 0.f, 0.f};
            *(float4*)&xt[ci][q * 4] = v;
        }
    }
    __syncthreads();

    const int c2 = t & 31;     // channel pair: channels 2*c2, 2*c2+1
    const int g  = t >> 5;     // node group 0..7 -> nodes g*16 .. g*16+15

    float aA0[16], aA1[16], aB0[16], aB1[16];
    #pragma unroll
    for (int j = 0; j < 16; j++) { aA0[j]=0.f; aA1[j]=0.f; aB0[j]=0.f; aB1[j]=0.f; }

    for (int ci = 0; ci < 64; ci++) {
        const float2 a  = *(const float2*)&At[ci][c2 * 2];
        const float2 w2 = *(const float2*)&Bt[ci][c2 * 2];
        const float4* xr = (const float4*)&xt[ci][g * 16];
        #pragma unroll
        for (int q = 0; q < 4; q++) {
            float4 xv = xr[q];
            aA0[q*4+0] += a.x*xv.x;  aA1[q*4+0] += a.y*xv.x;
            aB0[q*4+0] += w2.x*xv.x; aB1[q*4+0] += w2.y*xv.x;
            aA0[q*4+1] += a.x*xv.y;  aA1[q*4+1] += a.y*xv.y;
            aB0[q*4+1] += w2.x*xv.y; aB1[q*4+1] += w2.y*xv.y;
            aA0[q*4+2] += a.x*xv.z;  aA1[q*4+2] += a.y*xv.z;
            aB0[q*4+2] += w2.x*xv.z; aB1[q*4+2] += w2.y*xv.z;
            aA0[q*4+3] += a.x*xv.w;  aA1[q*4+3] += a.y*xv.w;
            aB0[q*4+3] += w2.x*xv.w; aB1[q*4+3] += w2.y*xv.w;
        }
    }

    const float b0 = b[c2 * 2], b1 = b[c2 * 2 + 1];
    unsigned int* yA32 = (unsigned int*)yA;   // [NN][32] channel-pairs
    unsigned int* yB32 = (unsigned int*)yB;
    #pragma unroll
    for (int j = 0; j < 16; j++) {
        const int n = n0 + g * 16 + j;
        if (n < NN) {
            yA32[n * 32 + c2] = (unsigned int)f2bf(aA0[j] + b0)
                              | ((unsigned int)f2bf(aA1[j] + b1) << 16);
            yB32[n * 32 + c2] = (unsigned int)f2bf(aB0[j])
                              | ((unsigned int)f2bf(aB1[j]) << 16);
        }
    }
}

// ---------------------------------------------------------------------------
// Kernel 2 (exact R3-best structure, 133.8 us total): 16 nodes/block,
// 4 nodes/wave, slot-parallel gather (4 edge slots x 16 channel-quads),
// shfl broadcasts, 10 uint2 gathers in flight per node.
// ---------------------------------------------------------------------------
__global__ __launch_bounds__(256) void edge_kernel(
    const ushort* __restrict__ yA,   // [NN][64] bf16  (x_i path, edge_index[1])
    const ushort* __restrict__ yB,   // [NN][64] bf16  (x_j path, edge_index[0])
    const int* __restrict__ ej,      // edge_index[0] : [NN][KK]
    const int* __restrict__ ei,      // edge_index[1] : [NN][KK]
    const float* __restrict__ dis,   // [NN][KK]
    const float* __restrict__ att_w, // [KK]
    const float* __restrict__ att_b, // [1]
    float* __restrict__ out)         // [64][NN]
{
    __shared__ float tile[16][68];

    const int t    = threadIdx.x;
    const int lane = t & 63;
    const int w    = t >> 6;            // wave 0..3
    const int g    = lane >> 4;         // edge slot 0..3
    const int l    = lane & 15;         // channel quad
    const int n0   = blockIdx.x * 16;   // grid 3125, no tail
    const int nb   = n0 + w * 4;

    const float aw = (lane < KK) ? att_w[lane] : 0.f;
    const float ab = att_b[0];

    float d4[4]; int ii4[4], jj4[4];
    #pragma unroll
    for (int s = 0; s < 4; s++) {
        const int n = nb + s;
        float d = 0.f; int ii = 0, jj = 0;
        if (lane < KK) {
            d  = dis[n * KK + lane];
            ii = ei[n * KK + lane];
            jj = ej[n * KK + lane];
        }
        d4[s] = d; ii4[s] = ii; jj4[s] = jj;
    }

    float sup4[4];
    #pragma unroll
    for (int s = 0; s < 4; s++) {
        float p = aw * d4[s];
        #pragma unroll
        for (int off = 16; off > 0; off >>= 1) p += __shfl_down(p, off);
        const float scaler = tanhf(__shfl(p, 0) + ab) + 1.0f;
        sup4[s] = 2.0f / (1.0f + __expf(d4[s] * scaler));  // valid lanes < 20
    }

    const uint2* A2 = (const uint2*)yA;   // 16 uint2 per node column
    const uint2* B2 = (const uint2*)yB;

    #pragma unroll
    for (int s = 0; s < 4; s++) {
        float4 m = {0.f, 0.f, 0.f, 0.f};
        #pragma unroll
        for (int kb = 0; kb < 5; kb++) {
            const int   src = kb * 4 + g;
            const int   i_k = __shfl(ii4[s], src);
            const int   j_k = __shfl(jj4[s], src);
            const float sp  = __shfl(sup4[s], src);
            const uint2 a  = A2[(size_t)i_k * 16 + l];
            const uint2 bb = B2[(size_t)j_k * 16 + l];
            float v;
            v = fmaxf(bfl(a.x) + bfl(bb.x), 0.f) * sp;  m.x = fmaxf(m.x, v);
            v = fmaxf(bfh(a.x) + bfh(bb.x), 0.f) * sp;  m.y = fmaxf(m.y, v);
            v = fmaxf(bfl(a.y) + bfl(bb.y), 0.f) * sp;  m.z = fmaxf(m.z, v);
            v = fmaxf(bfh(a.y) + bfh(bb.y), 0.f) * sp;  m.w = fmaxf(m.w, v);
        }
        #pragma unroll
        for (int mask = 16; mask <= 32; mask <<= 1) {
            m.x = fmaxf(m.x, __shfl_xor(m.x, mask));
            m.y = fmaxf(m.y, __shfl_xor(m.y, mask));
            m.z = fmaxf(m.z, __shfl_xor(m.z, mask));
            m.w = fmaxf(m.w, __shfl_xor(m.w, mask));
        }
        if (g == 0) *(float4*)&tile[w * 4 + s][l * 4] = m;
    }
    __syncthreads();

    #pragma unroll
    for (int it = 0; it < 4; it++) {
        const int c  = it * 16 + (t >> 4);
        const int nl = t & 15;
        out[(size_t)c * NN + n0 + nl] = tile[nl][c];
    }
}

extern "C" void kernel_launch(void* const* d_in, const int* in_sizes, int n_in,
                              void* d_out, int out_size, void* d_ws, size_t ws_size,
                              hipStream_t stream) {
    const float* x     = (const float*)d_in[0];
    const int*   e     = (const int*)d_in[1];    // [2][NN][KK]
    const float* dis   = (const float*)d_in[2];
    const float* W     = (const float*)d_in[3];
    const float* b     = (const float*)d_in[4];
    const float* att_w = (const float*)d_in[5];
    const float* att_b = (const float*)d_in[6];
    float* out = (float*)d_out;

    ushort* yA = (ushort*)d_ws;                  // [NN][64] bf16
    ushort* yB = yA + (size_t)NN * 64;           // [NN][64] bf16 (12.8 MB total)

    prep_kernel<<<(NN + 127) / 128, 256, 0, stream>>>(x, W, b, yA, yB);
    edge_kernel<<<NN / 16, 256, 0, stream>>>(yA, yB, e, e + NN * KK, dis,
                                             att_w, att_b, out);
}